// Round 4
// baseline (90.548 us; speedup 1.0000x reference)
//
#include <hip/hip_runtime.h>

#define DD 128

typedef __attribute__((ext_vector_type(8))) short bf16x8;
typedef __attribute__((ext_vector_type(4))) float f32x4;

__device__ __forceinline__ unsigned int cvt_pk_bf16(float lo, float hi) {
  unsigned int r;
  asm("v_cvt_pk_bf16_f32 %0, %1, %2" : "=v"(r) : "v"(lo), "v"(hi));
  return r;
}
__device__ __forceinline__ float bf_lo(unsigned int v) {
  return __uint_as_float(v << 16);
}
__device__ __forceinline__ float bf_hi(unsigned int v) {
  return __uint_as_float(v & 0xFFFF0000u);
}

// ---------------------------------------------------------------------------
// prep: CSR row offsets from sorted dst; B = concat(W[j][k], KG^T[j][k]) as bf16.
// ---------------------------------------------------------------------------
__global__ void prep_kernel(const int* __restrict__ dst, const float* __restrict__ W,
                            const float* __restrict__ KG, int* __restrict__ row_start,
                            unsigned short* __restrict__ B, int nEdges, int nNodes) {
  int e = blockIdx.x * 256 + threadIdx.x;
  if (e <= nEdges) {
    if (e == 0) {
      int d0 = dst[0];
      for (int n = 0; n <= d0; ++n) row_start[n] = 0;
    } else if (e == nEdges) {
      for (int n = dst[nEdges - 1] + 1; n <= nNodes; ++n) row_start[n] = nEdges;
    } else {
      int d = dst[e], dp = dst[e - 1];
      for (int n = dp + 1; n <= d; ++n) row_start[n] = e;
    }
  }
  if (e < 2 * DD * DD) {
    int j = e >> 7, k = e & 127;
    float v = (j < DD) ? W[j * DD + k] : KG[k * DD + (j - DD)];
    B[e] = (unsigned short)cvt_pk_bf16(v, v);
  }
}

// ---------------------------------------------------------------------------
// dual_gemm: [hidden | z] = x @ B^T  (M=100k, N=256, K=128), bf16 MFMA.
// OPERANDS SWAPPED vs r2: C[j][node] = B_rows x x_rows, so each thread's 4
// acc regs are 4 consecutive features j of ONE node -> 8B uint2 stores.
// 256 thr / 4 waves; tile 64 nodes; wave w -> features w*64..+63.
// B fragments in registers (L2-resident); LDS holds only x tile (16KB, swz).
// ---------------------------------------------------------------------------
__global__ __launch_bounds__(256, 3) void dual_gemm(
    const float* __restrict__ x, const unsigned short* __restrict__ B,
    const float* __restrict__ bias, const float* __restrict__ bg,
    unsigned short* __restrict__ hb, unsigned short* __restrict__ gw, int N) {
  __shared__ char smem[16 * 1024];
  unsigned short* sX = (unsigned short*)smem;
  int t = threadIdx.x;
  int wid = t >> 6, lane = t & 63;
  int M0 = blockIdx.x * 64;
  int jbw = wid * 64;  // feature base for this wave (0..255)
  int lr = lane & 15, lk = (lane >> 4) * 8;

  // ---- preload B-row fragments (A-operand): j = jbw + m*16 + lr
  bf16x8 bfr[4][4];  // [kc][m]
#pragma unroll
  for (int kc = 0; kc < 4; ++kc)
#pragma unroll
    for (int m = 0; m < 4; ++m)
      bfr[kc][m] = *(const bf16x8*)(B + (size_t)(jbw + m * 16 + lr) * DD + kc * 32 + lk);

  // ---- stage x tile (f32 -> bf16 via cvt_pk, swizzled): 2048 float4
#pragma unroll
  for (int i = 0; i < 8; ++i) {
    int f4 = i * 256 + t;
    int r = f4 >> 5;
    int kk = (f4 & 31) * 4;
    float4 v;
    if (M0 + r < N) v = ((const float4*)x)[(size_t)(M0 + r) * 32 + (f4 & 31)];
    else            v = make_float4(0.f, 0.f, 0.f, 0.f);
    unsigned int lo = cvt_pk_bf16(v.x, v.y);
    unsigned int hi = cvt_pk_bf16(v.z, v.w);
    int off = (r * 256 + kk * 2) ^ ((r & 7) << 4);
    uint2 q = {lo, hi};
    *(uint2*)((char*)sX + off) = q;
  }
  __syncthreads();

  f32x4 acc[4][4];  // [m = j-block][nr = node-block]
#pragma unroll
  for (int m = 0; m < 4; ++m)
#pragma unroll
    for (int nr = 0; nr < 4; ++nr) acc[m][nr] = (f32x4){0.f, 0.f, 0.f, 0.f};

#pragma unroll
  for (int kc = 0; kc < 4; ++kc) {
    int kb = (kc * 32 + lk) * 2;
    bf16x8 xf[4];  // B-operand: x rows (nodes)
#pragma unroll
    for (int nr = 0; nr < 4; ++nr) {
      int r = nr * 16 + lr;
      xf[nr] = *(const bf16x8*)((const char*)sX + ((r * 256 + kb) ^ ((r & 7) << 4)));
    }
#pragma unroll
    for (int m = 0; m < 4; ++m)
#pragma unroll
      for (int nr = 0; nr < 4; ++nr)
        acc[m][nr] = __builtin_amdgcn_mfma_f32_16x16x32_bf16(bfr[kc][m], xf[nr], acc[m][nr], 0, 0, 0);
  }

  // ---- epilogue: C row = j = jbw + m*16 + (lane>>4)*4 + reg; col = node.
  bool isGate = (wid >= 2);
  unsigned short* dbuf = isGate ? gw : hb;
  const float* bvec = isGate ? bg : bias;
  int jb = jbw - (isGate ? 128 : 0);  // feature base within 128-wide buffer
#pragma unroll
  for (int m = 0; m < 4; ++m) {
    int j0 = jb + m * 16 + ((lane >> 4) << 2);
    float4 b4 = *(const float4*)&bvec[j0];
#pragma unroll
    for (int nr = 0; nr < 4; ++nr) {
      int node = M0 + nr * 16 + lr;
      f32x4 v = acc[m][nr];
      float z0 = v[0] + b4.x, z1 = v[1] + b4.y, z2 = v[2] + b4.z, z3 = v[3] + b4.w;
      if (isGate) {
        z0 = 1.0f / (1.0f + __expf(-z0));
        z1 = 1.0f / (1.0f + __expf(-z1));
        z2 = 1.0f / (1.0f + __expf(-z2));
        z3 = 1.0f / (1.0f + __expf(-z3));
      }
      uint2 q = {cvt_pk_bf16(z0, z1), cvt_pk_bf16(z2, z3)};
      if (node < N) *(uint2*)&dbuf[(size_t)node * DD + j0] = q;
    }
  }
}

// ---------------------------------------------------------------------------
// scatter_combine: support = relu(segment_sum(ew * hb[src])),
// out = gate*support + (1-gate)*x.  One wave per node; lane = 2 cols (u32 row).
// ---------------------------------------------------------------------------
__global__ __launch_bounds__(256, 8) void scatter_combine(
    const unsigned short* __restrict__ hb, const unsigned short* __restrict__ gw,
    const float* __restrict__ x, const int* __restrict__ src,
    const float* __restrict__ ew, const int* __restrict__ row_start,
    float* __restrict__ out) {
  int w = threadIdx.x >> 6;
  int lane = threadIdx.x & 63;
  int n = blockIdx.x * 4 + w;
  int b = __builtin_amdgcn_readfirstlane(row_start[n]);
  int e = __builtin_amdgcn_readfirstlane(row_start[n + 1]);
  const unsigned int* h32 = (const unsigned int*)hb;

  unsigned int g2 = ((const unsigned int*)gw)[(size_t)n * 64 + lane];
  float2 xv = *(const float2*)&x[(size_t)n * DD + lane * 2];

  float a0x = 0.f, a0y = 0.f, a1x = 0.f, a1y = 0.f;
  float a2x = 0.f, a2y = 0.f, a3x = 0.f, a3y = 0.f;
  int i = b;
  for (; i + 4 <= e; i += 4) {
    int s0 = src[i], s1 = src[i + 1], s2 = src[i + 2], s3 = src[i + 3];
    float w0 = ew[i], w1 = ew[i + 1], w2 = ew[i + 2], w3 = ew[i + 3];
    unsigned int v0 = h32[(size_t)s0 * 64 + lane];
    unsigned int v1 = h32[(size_t)s1 * 64 + lane];
    unsigned int v2 = h32[(size_t)s2 * 64 + lane];
    unsigned int v3 = h32[(size_t)s3 * 64 + lane];
    a0x += w0 * bf_lo(v0); a0y += w0 * bf_hi(v0);
    a1x += w1 * bf_lo(v1); a1y += w1 * bf_hi(v1);
    a2x += w2 * bf_lo(v2); a2y += w2 * bf_hi(v2);
    a3x += w3 * bf_lo(v3); a3y += w3 * bf_hi(v3);
  }
  for (; i < e; ++i) {
    int s = src[i];
    float wt = ew[i];
    unsigned int v = h32[(size_t)s * 64 + lane];
    a0x += wt * bf_lo(v); a0y += wt * bf_hi(v);
  }
  float sx = fmaxf(a0x + a1x + a2x + a3x, 0.f);
  float sy = fmaxf(a0y + a1y + a2y + a3y, 0.f);

  float gx = bf_lo(g2), gy = bf_hi(g2);
  float2 o;
  o.x = gx * sx + (1.f - gx) * xv.x;
  o.y = gy * sy + (1.f - gy) * xv.y;
  *(float2*)&out[(size_t)n * DD + lane * 2] = o;
}

// ---------------------------------------------------------------------------
extern "C" void kernel_launch(void* const* d_in, const int* in_sizes, int n_in,
                              void* d_out, int out_size, void* d_ws, size_t ws_size,
                              hipStream_t stream) {
  const float* x   = (const float*)d_in[0];
  const int*   src = (const int*)d_in[1];
  const int*   dst = (const int*)d_in[2];
  const float* ew  = (const float*)d_in[3];
  const float* W   = (const float*)d_in[4];
  const float* b   = (const float*)d_in[5];
  const float* KG  = (const float*)d_in[6];
  const float* bg  = (const float*)d_in[7];
  float* out = (float*)d_out;

  int N = in_sizes[0] / DD;
  int E = in_sizes[1];

  unsigned short* hb = (unsigned short*)d_ws;              // N*128 bf16
  unsigned short* gw = hb + (size_t)N * DD;                // N*128 bf16
  unsigned short* B  = gw + (size_t)N * DD;                // 256*128 bf16
  int* row_start = (int*)(B + 2 * DD * DD);                // N+1 ints

  int prepBlocks = (E + 1 + 255) / 256;
  prep_kernel<<<prepBlocks, 256, 0, stream>>>(dst, W, KG, row_start, B, E, N);
  dual_gemm<<<(N + 63) / 64, 256, 0, stream>>>(x, B, b, bg, hb, gw, N);
  scatter_combine<<<N / 4, 256, 0, stream>>>(hb, gw, x, src, ew, row_start, out);
}

// Round 5
// 83.706 us; speedup vs baseline: 1.0817x; 1.0817x over previous
//
#include <hip/hip_runtime.h>

#define DD 128

typedef __attribute__((ext_vector_type(8))) short bf16x8;
typedef __attribute__((ext_vector_type(4))) float f32x4;

__device__ __forceinline__ unsigned int cvt_pk_bf16(float lo, float hi) {
  unsigned int r;
  asm("v_cvt_pk_bf16_f32 %0, %1, %2" : "=v"(r) : "v"(lo), "v"(hi));
  return r;
}
__device__ __forceinline__ float bf_lo(unsigned int v) { return __uint_as_float(v << 16); }
__device__ __forceinline__ float bf_hi(unsigned int v) { return __uint_as_float(v & 0xFFFF0000u); }

// ---------------------------------------------------------------------------
// prep: (a) xb = bf16(x); (b) CSR row offsets from sorted dst;
//       (c) B = [ W[j][k] ; KG^T[j][k] ] as bf16. Index-partitioned jobs.
// ---------------------------------------------------------------------------
__global__ void prep_kernel(const float* __restrict__ x, const int* __restrict__ dst,
                            const float* __restrict__ W, const float* __restrict__ KG,
                            unsigned short* __restrict__ xb, int* __restrict__ row_start,
                            unsigned short* __restrict__ B, int N, int E) {
  int i = blockIdx.x * 256 + threadIdx.x;
  int NC = N * (DD / 4);  // float4 items of x
  if (i < NC) {
    float4 v = ((const float4*)x)[i];
    uint2 q = {cvt_pk_bf16(v.x, v.y), cvt_pk_bf16(v.z, v.w)};
    ((uint2*)xb)[i] = q;
  } else if (i < NC + E + 1) {
    int e = i - NC;
    if (e == 0) {
      int d0 = dst[0];
      for (int n = 0; n <= d0; ++n) row_start[n] = 0;
    } else if (e == E) {
      for (int n = dst[E - 1] + 1; n <= N; ++n) row_start[n] = E;
    } else {
      int d = dst[e], dp = dst[e - 1];
      for (int n = dp + 1; n <= d; ++n) row_start[n] = e;
    }
  } else if (i < NC + E + 1 + 2 * DD * DD) {
    int e2 = i - (NC + E + 1);
    int j = e2 >> 7, k = e2 & 127;
    float v = (j < DD) ? W[j * DD + k] : KG[k * DD + (j - DD)];
    B[e2] = (unsigned short)cvt_pk_bf16(v, v);
  }
}

// ---------------------------------------------------------------------------
// scatter_agg: aggb[n] = bf16( sum_{e:dst=n} ew_e * xb[src_e] ), sumw[n] = sum ew_e.
// One wave per node; lane covers 2 bf16 cols (u32 -> coalesced 256B row reads).
// ---------------------------------------------------------------------------
__global__ __launch_bounds__(256, 8) void scatter_agg(
    const unsigned short* __restrict__ xb, const int* __restrict__ src,
    const float* __restrict__ ew, const int* __restrict__ row_start,
    unsigned short* __restrict__ aggb, float* __restrict__ sumw) {
  int w = threadIdx.x >> 6;
  int lane = threadIdx.x & 63;
  int n = blockIdx.x * 4 + w;
  int b = __builtin_amdgcn_readfirstlane(row_start[n]);
  int e = __builtin_amdgcn_readfirstlane(row_start[n + 1]);
  const unsigned int* x32 = (const unsigned int*)xb;

  float a0x = 0.f, a0y = 0.f, a1x = 0.f, a1y = 0.f;
  float a2x = 0.f, a2y = 0.f, a3x = 0.f, a3y = 0.f;
  float ws_ = 0.f;
  int i = b;
  for (; i + 4 <= e; i += 4) {
    int s0 = src[i], s1 = src[i + 1], s2 = src[i + 2], s3 = src[i + 3];
    float w0 = ew[i], w1 = ew[i + 1], w2 = ew[i + 2], w3 = ew[i + 3];
    unsigned int v0 = x32[(size_t)s0 * 64 + lane];
    unsigned int v1 = x32[(size_t)s1 * 64 + lane];
    unsigned int v2 = x32[(size_t)s2 * 64 + lane];
    unsigned int v3 = x32[(size_t)s3 * 64 + lane];
    a0x += w0 * bf_lo(v0); a0y += w0 * bf_hi(v0);
    a1x += w1 * bf_lo(v1); a1y += w1 * bf_hi(v1);
    a2x += w2 * bf_lo(v2); a2y += w2 * bf_hi(v2);
    a3x += w3 * bf_lo(v3); a3y += w3 * bf_hi(v3);
    ws_ += w0 + w1 + w2 + w3;
  }
  for (; i < e; ++i) {
    int s = src[i];
    float wt = ew[i];
    unsigned int v = x32[(size_t)s * 64 + lane];
    a0x += wt * bf_lo(v); a0y += wt * bf_hi(v);
    ws_ += wt;
  }
  float ax = a0x + a1x + a2x + a3x;
  float ay = a0y + a1y + a2y + a3y;
  ((unsigned int*)aggb)[(size_t)n * 64 + lane] = cvt_pk_bf16(ax, ay);
  if (lane == 0) sumw[n] = ws_;
}

// ---------------------------------------------------------------------------
// fused_gemm: per 64-node tile:
//   S = relu(aggb @ W^T + sumw*b);  G = sigmoid(xb @ KG + bg);
//   out = G*S + (1-G)*xb          (one f32 write, no intermediates)
// 256 thr / 4 waves; wave w owns features w*32..+31 of BOTH gemms.
// Swapped MFMA operands (C[j][node]) so each thread's acc = 4 consecutive j
// of one node -> float4 out stores. LDS: xb tile + agg tile (32KB, swizzled).
// ---------------------------------------------------------------------------
__global__ __launch_bounds__(256, 2) void fused_gemm(
    const unsigned short* __restrict__ xb, const unsigned short* __restrict__ aggb,
    const unsigned short* __restrict__ B, const float* __restrict__ sumw,
    const float* __restrict__ bias, const float* __restrict__ bg,
    float* __restrict__ out, int N) {
  __shared__ char smem[32 * 1024];
  unsigned short* sX = (unsigned short*)smem;            // 16KB: xb tile
  unsigned short* sA = (unsigned short*)(smem + 16384);  // 16KB: agg tile
  int t = threadIdx.x;
  int wid = t >> 6, lane = t & 63;
  int lr = lane & 15, lk2 = lane >> 4;
  int jw = wid * 32;
  int M0 = blockIdx.x * 64;

  // ---- persistent A-operand fragments: W rows (support) and KG^T rows (gate)
  bf16x8 wS[4][2], wG[4][2];  // [kc][m]
#pragma unroll
  for (int kc = 0; kc < 4; ++kc)
#pragma unroll
    for (int m = 0; m < 2; ++m) {
      int j = jw + m * 16 + lr;
      wS[kc][m] = *(const bf16x8*)(B + (size_t)j * DD + kc * 32 + lk2 * 8);
      wG[kc][m] = *(const bf16x8*)(B + (size_t)(DD + j) * DD + kc * 32 + lk2 * 8);
    }
  float b4[2][4], bg4[2][4];
#pragma unroll
  for (int m = 0; m < 2; ++m) {
    *(float4*)b4[m]  = *(const float4*)&bias[jw + m * 16 + lk2 * 4];
    *(float4*)bg4[m] = *(const float4*)&bg[jw + m * 16 + lk2 * 4];
  }

  // ---- stage xb + agg tiles (1024 uint4 each, swizzled)
#pragma unroll
  for (int i = 0; i < 4; ++i) {
    int idx = i * 256 + t;
    int r = idx >> 4, c = idx & 15;
    uint4 vx, va;
    if (M0 + r < N) {
      vx = ((const uint4*)(xb + (size_t)(M0 + r) * DD))[c];
      va = ((const uint4*)(aggb + (size_t)(M0 + r) * DD))[c];
    } else {
      vx = make_uint4(0, 0, 0, 0);
      va = make_uint4(0, 0, 0, 0);
    }
    int off = (r * 256 + c * 16) ^ ((r & 7) << 4);
    *(uint4*)((char*)sX + off) = vx;
    *(uint4*)((char*)sA + off) = va;
  }
  __syncthreads();

  f32x4 accS[2][4], accG[2][4];
#pragma unroll
  for (int m = 0; m < 2; ++m)
#pragma unroll
    for (int nr = 0; nr < 4; ++nr) {
      accS[m][nr] = (f32x4){0.f, 0.f, 0.f, 0.f};
      accG[m][nr] = (f32x4){0.f, 0.f, 0.f, 0.f};
    }

#pragma unroll
  for (int kc = 0; kc < 4; ++kc) {
    int kb = (kc * 32 + lk2 * 8) * 2;
    bf16x8 af[4], xf[4];
#pragma unroll
    for (int nr = 0; nr < 4; ++nr) {
      int r = nr * 16 + lr;
      int off = (r * 256 + kb) ^ ((r & 7) << 4);
      af[nr] = *(const bf16x8*)((const char*)sA + off);
      xf[nr] = *(const bf16x8*)((const char*)sX + off);
    }
#pragma unroll
    for (int m = 0; m < 2; ++m)
#pragma unroll
      for (int nr = 0; nr < 4; ++nr) {
        accS[m][nr] = __builtin_amdgcn_mfma_f32_16x16x32_bf16(wS[kc][m], af[nr], accS[m][nr], 0, 0, 0);
        accG[m][nr] = __builtin_amdgcn_mfma_f32_16x16x32_bf16(wG[kc][m], xf[nr], accG[m][nr], 0, 0, 0);
      }
  }

  // ---- epilogue: j0 = jw + m*16 + lk2*4 + reg; node = M0 + nr*16 + lr
#pragma unroll
  for (int m = 0; m < 2; ++m) {
    int j0 = jw + m * 16 + lk2 * 4;
#pragma unroll
    for (int nr = 0; nr < 4; ++nr) {
      int node = M0 + nr * 16 + lr;
      if (node < N) {
        float sw = sumw[node];
        int r = nr * 16 + lr;
        uint2 qx = *(const uint2*)((const char*)sX + ((r * 256 + j0 * 2) ^ ((r & 7) << 4)));
        float xr[4] = {bf_lo(qx.x), bf_hi(qx.x), bf_lo(qx.y), bf_hi(qx.y)};
        f32x4 vs = accS[m][nr], vg = accG[m][nr];
        float4 o;
        float* op = &o.x;
#pragma unroll
        for (int reg = 0; reg < 4; ++reg) {
          float s = fmaxf(vs[reg] + sw * b4[m][reg], 0.f);
          float g = 1.0f / (1.0f + __expf(-(vg[reg] + bg4[m][reg])));
          op[reg] = g * s + (1.0f - g) * xr[reg];
        }
        *(float4*)&out[(size_t)node * DD + j0] = o;
      }
    }
  }
}

// ---------------------------------------------------------------------------
extern "C" void kernel_launch(void* const* d_in, const int* in_sizes, int n_in,
                              void* d_out, int out_size, void* d_ws, size_t ws_size,
                              hipStream_t stream) {
  const float* x   = (const float*)d_in[0];
  const int*   src = (const int*)d_in[1];
  const int*   dst = (const int*)d_in[2];
  const float* ew  = (const float*)d_in[3];
  const float* W   = (const float*)d_in[4];
  const float* b   = (const float*)d_in[5];
  const float* KG  = (const float*)d_in[6];
  const float* bg  = (const float*)d_in[7];
  float* out = (float*)d_out;

  int N = in_sizes[0] / DD;
  int E = in_sizes[1];

  unsigned short* xbuf = (unsigned short*)d_ws;            // N*128 bf16
  unsigned short* aggb = xbuf + (size_t)N * DD;            // N*128 bf16
  unsigned short* B    = aggb + (size_t)N * DD;            // 2*128*128 bf16
  float* sumw = (float*)(B + 2 * DD * DD);                 // N f32
  int* row_start = (int*)(sumw + N);                       // N+1 ints

  int totalPrep = N * (DD / 4) + (E + 1) + 2 * DD * DD;
  prep_kernel<<<(totalPrep + 255) / 256, 256, 0, stream>>>(x, dst, W, KG, xbuf, row_start, B, N, E);
  scatter_agg<<<N / 4, 256, 0, stream>>>(xbuf, src, ew, row_start, aggb, sumw);
  fused_gemm<<<(N + 63) / 64, 256, 0, stream>>>(xbuf, aggb, B, sumw, b, bg, out, N);
}

// Round 6
// 81.733 us; speedup vs baseline: 1.1079x; 1.0241x over previous
//
#include <hip/hip_runtime.h>

#define DD 128

typedef __attribute__((ext_vector_type(8))) short bf16x8;
typedef __attribute__((ext_vector_type(4))) float f32x4;

__device__ __forceinline__ unsigned int cvt_pk_bf16(float lo, float hi) {
  unsigned int r;
  asm("v_cvt_pk_bf16_f32 %0, %1, %2" : "=v"(r) : "v"(lo), "v"(hi));
  return r;
}
__device__ __forceinline__ float bf_lo(unsigned int v) { return __uint_as_float(v << 16); }
__device__ __forceinline__ float bf_hi(unsigned int v) { return __uint_as_float(v & 0xFFFF0000u); }

// ---------------------------------------------------------------------------
// prep: (a) xb = bf16(x); (b) CSR row offsets from sorted dst;
//       (c) B = [ W[j][k] ; KG^T[j][k] ] as bf16. Index-partitioned jobs.
// ---------------------------------------------------------------------------
__global__ void prep_kernel(const float* __restrict__ x, const int* __restrict__ dst,
                            const float* __restrict__ W, const float* __restrict__ KG,
                            unsigned short* __restrict__ xb, int* __restrict__ row_start,
                            unsigned short* __restrict__ B, int N, int E) {
  int i = blockIdx.x * 256 + threadIdx.x;
  int NC = N * (DD / 4);  // float4 items of x
  if (i < NC) {
    float4 v = ((const float4*)x)[i];
    uint2 q = {cvt_pk_bf16(v.x, v.y), cvt_pk_bf16(v.z, v.w)};
    ((uint2*)xb)[i] = q;
  } else if (i < NC + E + 1) {
    int e = i - NC;
    if (e == 0) {
      int d0 = dst[0];
      for (int n = 0; n <= d0; ++n) row_start[n] = 0;
    } else if (e == E) {
      for (int n = dst[E - 1] + 1; n <= N; ++n) row_start[n] = E;
    } else {
      int d = dst[e], dp = dst[e - 1];
      for (int n = dp + 1; n <= d; ++n) row_start[n] = e;
    }
  } else if (i < NC + E + 1 + 2 * DD * DD) {
    int e2 = i - (NC + E + 1);
    int j = e2 >> 7, k = e2 & 127;
    float v = (j < DD) ? W[j * DD + k] : KG[k * DD + (j - DD)];
    B[e2] = (unsigned short)cvt_pk_bf16(v, v);
  }
}

// ---------------------------------------------------------------------------
// scatter_agg v2: aggb[n] = bf16(sum ew_e * xb[src_e]), sumw[n] = sum ew_e.
// 4 nodes per wave (16 lanes each, uint4 = 16B/lane -> coalesced 256B row).
// 4-edge unroll keeps 4 whole-wave gathers (16 node-streams) in flight.
// Finished quarters: wt=0, address clamped to own last edge (L1-hit).
// ---------------------------------------------------------------------------
__global__ __launch_bounds__(256, 8) void scatter_agg(
    const unsigned short* __restrict__ xb, const int* __restrict__ src,
    const float* __restrict__ ew, const int* __restrict__ row_start,
    unsigned short* __restrict__ aggb, float* __restrict__ sumw, int N, int E) {
  int t = threadIdx.x;
  int wid = t >> 6, lane = t & 63;
  int q = lane >> 4, lr = lane & 15;
  int n = blockIdx.x * 16 + wid * 4 + q;
  bool valid = (n < N);
  int b = valid ? row_start[n] : 0;
  int cnt = valid ? (row_start[n + 1] - b) : 0;
  const uint4* x16 = (const uint4*)xb;

  float a[8];
#pragma unroll
  for (int k = 0; k < 8; ++k) a[k] = 0.f;
  float wsum = 0.f;
  int clampj = cnt > 0 ? cnt - 1 : 0;

  int i = 0;
  while (__any(i < cnt)) {
#pragma unroll
    for (int u = 0; u < 4; ++u) {
      int ii = i + u;
      int jj = ii < clampj ? ii : clampj;
      int j = b + jj;
      if (j > E - 1) j = E - 1;
      float wt = (ii < cnt) ? ew[j] : 0.f;
      int s = src[j];
      uint4 v = x16[(size_t)s * 16 + lr];
      wsum += wt;
      a[0] += wt * bf_lo(v.x); a[1] += wt * bf_hi(v.x);
      a[2] += wt * bf_lo(v.y); a[3] += wt * bf_hi(v.y);
      a[4] += wt * bf_lo(v.z); a[5] += wt * bf_hi(v.z);
      a[6] += wt * bf_lo(v.w); a[7] += wt * bf_hi(v.w);
    }
    i += 4;
  }

  if (valid) {
    uint4 o;
    o.x = cvt_pk_bf16(a[0], a[1]);
    o.y = cvt_pk_bf16(a[2], a[3]);
    o.z = cvt_pk_bf16(a[4], a[5]);
    o.w = cvt_pk_bf16(a[6], a[7]);
    ((uint4*)aggb)[(size_t)n * 16 + lr] = o;
    if (lr == 0) sumw[n] = wsum;
  }
}

// ---------------------------------------------------------------------------
// fused_gemm: per 64-node tile:
//   S = relu(aggb @ W^T + sumw*b);  G = sigmoid(xb @ KG + bg);
//   out = G*S + (1-G)*xb          (one f32 write, no intermediates)
// 256 thr / 4 waves; wave w owns features w*32..+31 of BOTH gemms.
// Swapped MFMA operands (C[j][node]) so each thread's acc = 4 consecutive j
// of one node -> float4 out stores. LDS: xb tile + agg tile (32KB, swizzled).
// ---------------------------------------------------------------------------
__global__ __launch_bounds__(256, 2) void fused_gemm(
    const unsigned short* __restrict__ xb, const unsigned short* __restrict__ aggb,
    const unsigned short* __restrict__ B, const float* __restrict__ sumw,
    const float* __restrict__ bias, const float* __restrict__ bg,
    float* __restrict__ out, int N) {
  __shared__ char smem[32 * 1024];
  unsigned short* sX = (unsigned short*)smem;            // 16KB: xb tile
  unsigned short* sA = (unsigned short*)(smem + 16384);  // 16KB: agg tile
  int t = threadIdx.x;
  int wid = t >> 6, lane = t & 63;
  int lr = lane & 15, lk2 = lane >> 4;
  int jw = wid * 32;
  int M0 = blockIdx.x * 64;

  // ---- persistent A-operand fragments: W rows (support) and KG^T rows (gate)
  bf16x8 wS[4][2], wG[4][2];  // [kc][m]
#pragma unroll
  for (int kc = 0; kc < 4; ++kc)
#pragma unroll
    for (int m = 0; m < 2; ++m) {
      int j = jw + m * 16 + lr;
      wS[kc][m] = *(const bf16x8*)(B + (size_t)j * DD + kc * 32 + lk2 * 8);
      wG[kc][m] = *(const bf16x8*)(B + (size_t)(DD + j) * DD + kc * 32 + lk2 * 8);
    }
  float b4[2][4], bg4[2][4];
#pragma unroll
  for (int m = 0; m < 2; ++m) {
    *(float4*)b4[m]  = *(const float4*)&bias[jw + m * 16 + lk2 * 4];
    *(float4*)bg4[m] = *(const float4*)&bg[jw + m * 16 + lk2 * 4];
  }

  // ---- stage xb + agg tiles (1024 uint4 each, swizzled)
#pragma unroll
  for (int i = 0; i < 4; ++i) {
    int idx = i * 256 + t;
    int r = idx >> 4, c = idx & 15;
    uint4 vx, va;
    if (M0 + r < N) {
      vx = ((const uint4*)(xb + (size_t)(M0 + r) * DD))[c];
      va = ((const uint4*)(aggb + (size_t)(M0 + r) * DD))[c];
    } else {
      vx = make_uint4(0, 0, 0, 0);
      va = make_uint4(0, 0, 0, 0);
    }
    int off = (r * 256 + c * 16) ^ ((r & 7) << 4);
    *(uint4*)((char*)sX + off) = vx;
    *(uint4*)((char*)sA + off) = va;
  }
  __syncthreads();

  f32x4 accS[2][4], accG[2][4];
#pragma unroll
  for (int m = 0; m < 2; ++m)
#pragma unroll
    for (int nr = 0; nr < 4; ++nr) {
      accS[m][nr] = (f32x4){0.f, 0.f, 0.f, 0.f};
      accG[m][nr] = (f32x4){0.f, 0.f, 0.f, 0.f};
    }

#pragma unroll
  for (int kc = 0; kc < 4; ++kc) {
    int kb = (kc * 32 + lk2 * 8) * 2;
    bf16x8 af[4], xf[4];
#pragma unroll
    for (int nr = 0; nr < 4; ++nr) {
      int r = nr * 16 + lr;
      int off = (r * 256 + kb) ^ ((r & 7) << 4);
      af[nr] = *(const bf16x8*)((const char*)sA + off);
      xf[nr] = *(const bf16x8*)((const char*)sX + off);
    }
#pragma unroll
    for (int m = 0; m < 2; ++m)
#pragma unroll
      for (int nr = 0; nr < 4; ++nr) {
        accS[m][nr] = __builtin_amdgcn_mfma_f32_16x16x32_bf16(wS[kc][m], af[nr], accS[m][nr], 0, 0, 0);
        accG[m][nr] = __builtin_amdgcn_mfma_f32_16x16x32_bf16(wG[kc][m], xf[nr], accG[m][nr], 0, 0, 0);
      }
  }

  // ---- epilogue: j0 = jw + m*16 + lk2*4 + reg; node = M0 + nr*16 + lr
#pragma unroll
  for (int m = 0; m < 2; ++m) {
    int j0 = jw + m * 16 + lk2 * 4;
#pragma unroll
    for (int nr = 0; nr < 4; ++nr) {
      int node = M0 + nr * 16 + lr;
      if (node < N) {
        float sw = sumw[node];
        int r = nr * 16 + lr;
        uint2 qx = *(const uint2*)((const char*)sX + ((r * 256 + j0 * 2) ^ ((r & 7) << 4)));
        float xr[4] = {bf_lo(qx.x), bf_hi(qx.x), bf_lo(qx.y), bf_hi(qx.y)};
        f32x4 vs = accS[m][nr], vg = accG[m][nr];
        float4 o;
        float* op = &o.x;
#pragma unroll
        for (int reg = 0; reg < 4; ++reg) {
          float s = fmaxf(vs[reg] + sw * b4[m][reg], 0.f);
          float g = 1.0f / (1.0f + __expf(-(vg[reg] + bg4[m][reg])));
          op[reg] = g * s + (1.0f - g) * xr[reg];
        }
        *(float4*)&out[(size_t)node * DD + j0] = o;
      }
    }
  }
}

// ---------------------------------------------------------------------------
extern "C" void kernel_launch(void* const* d_in, const int* in_sizes, int n_in,
                              void* d_out, int out_size, void* d_ws, size_t ws_size,
                              hipStream_t stream) {
  const float* x   = (const float*)d_in[0];
  const int*   src = (const int*)d_in[1];
  const int*   dst = (const int*)d_in[2];
  const float* ew  = (const float*)d_in[3];
  const float* W   = (const float*)d_in[4];
  const float* b   = (const float*)d_in[5];
  const float* KG  = (const float*)d_in[6];
  const float* bg  = (const float*)d_in[7];
  float* out = (float*)d_out;

  int N = in_sizes[0] / DD;
  int E = in_sizes[1];

  unsigned short* xbuf = (unsigned short*)d_ws;            // N*128 bf16
  unsigned short* aggb = xbuf + (size_t)N * DD;            // N*128 bf16
  unsigned short* B    = aggb + (size_t)N * DD;            // 2*128*128 bf16
  float* sumw = (float*)(B + 2 * DD * DD);                 // N f32
  int* row_start = (int*)(sumw + N);                       // N+1 ints

  int totalPrep = N * (DD / 4) + (E + 1) + 2 * DD * DD;
  prep_kernel<<<(totalPrep + 255) / 256, 256, 0, stream>>>(x, dst, W, KG, xbuf, row_start, B, N, E);
  scatter_agg<<<(N + 15) / 16, 256, 0, stream>>>(xbuf, src, ew, row_start, aggb, sumw, N, E);
  fused_gemm<<<(N + 63) / 64, 256, 0, stream>>>(xbuf, aggb, B, sumw, b, bg, out, N);
}